// Round 1
// baseline (78.968 us; speedup 1.0000x reference)
//
#include <hip/hip_runtime.h>

// CP embedding: out[t, emb] = sum_r U0[a,r]U1[b,r]U2[c,r] * U3[d,r]U4[e,r]U5[f,r]
// where x[t] = a*1000 + b*25 + c  (a<50,b<40,c<25), emb = d*64 + e*8 + f.
// Rows with x[t]==0 (padding) are zero.
//
// Shapes: U0 (50,32) U1 (40,32) U2 (25,32) U3/U4/U5 (8,32), x (4,2048) int32,
// out (8192, 512) fp32.  Store-BW bound: 16 MB out, ~268 MFLOP fp32.

#define RANK 32
#define EMB 512
#define NTOK 8192
#define TOK_PER_BLK 32
#define EMB_CHUNK 128

__global__ __launch_bounds__(256) void cp_embed_kernel(
    const float* __restrict__ U0, const float* __restrict__ U1,
    const float* __restrict__ U2, const float* __restrict__ U3,
    const float* __restrict__ U4, const float* __restrict__ U5,
    const int*   __restrict__ x,  float* __restrict__ out)
{
    __shared__ float Wlds[RANK][EMB_CHUNK];     // [r][e_local] slice of W345^T
    __shared__ float wlds[TOK_PER_BLK][RANK];   // [t_local][r] token rank-vectors

    const int tid = threadIdx.x;
    const int c   = blockIdx.x & 3;   // emb chunk: [c*128, c*128+128)
    const int g   = blockIdx.x >> 2;  // token group: [g*32, g*32+32)

    // ---- Phase 1: build this block's 32x128 slice of W345^T in LDS ----
    #pragma unroll
    for (int k = 0; k < 16; ++k) {
        int i = tid + k * 256;            // 0..4095
        int e = i & 127;
        int r = i >> 7;
        int eg = c * EMB_CHUNK + e;       // global emb index
        int d  = eg >> 6;
        int e2 = (eg >> 3) & 7;
        int f  = eg & 7;
        Wlds[r][e] = U3[d * RANK + r] * U4[e2 * RANK + r] * U5[f * RANK + r];
    }

    // ---- Phase 2: build the group's 32 token rank-vectors in LDS ----
    #pragma unroll
    for (int k = 0; k < 4; ++k) {
        int i  = tid + k * 256;           // 0..1023
        int tl = i >> 5;
        int r  = i & 31;
        int v  = x[g * TOK_PER_BLK + tl];
        float wv = 0.0f;
        if (v != 0) {                     // padding_idx = 0 -> zero row
            int a   = v / 1000;
            int rem = v - a * 1000;
            int b   = rem / 25;
            int cc  = rem - b * 25;
            wv = U0[a * RANK + r] * U1[b * RANK + r] * U2[cc * RANK + r];
        }
        wlds[tl][r] = wv;
    }

    __syncthreads();

    // ---- Phase 3: each thread owns a fixed float2 emb-slice in registers ----
    const int lane_e = (tid & 63) * 2;    // emb offset within chunk (0..126)
    const int ts     = tid >> 6;          // token sub-slice 0..3 (wave-uniform)

    float2 wt[RANK];
    #pragma unroll
    for (int r = 0; r < RANK; ++r)
        wt[r] = *reinterpret_cast<const float2*>(&Wlds[r][lane_e]);

    for (int tt = ts; tt < TOK_PER_BLK; tt += 4) {
        const float4* w4 = reinterpret_cast<const float4*>(wlds[tt]); // broadcast
        float accx = 0.0f, accy = 0.0f;
        #pragma unroll
        for (int rr = 0; rr < 8; ++rr) {
            float4 wv = w4[rr];
            accx += wv.x * wt[4*rr+0].x;  accy += wv.x * wt[4*rr+0].y;
            accx += wv.y * wt[4*rr+1].x;  accy += wv.y * wt[4*rr+1].y;
            accx += wv.z * wt[4*rr+2].x;  accy += wv.z * wt[4*rr+2].y;
            accx += wv.w * wt[4*rr+3].x;  accy += wv.w * wt[4*rr+3].y;
        }
        int t = g * TOK_PER_BLK + tt;
        float2 o = make_float2(accx, accy);
        *reinterpret_cast<float2*>(&out[t * EMB + c * EMB_CHUNK + lane_e]) = o;
    }
}

extern "C" void kernel_launch(void* const* d_in, const int* in_sizes, int n_in,
                              void* d_out, int out_size, void* d_ws, size_t ws_size,
                              hipStream_t stream) {
    const float* U0 = (const float*)d_in[0];
    const float* U1 = (const float*)d_in[1];
    const float* U2 = (const float*)d_in[2];
    const float* U3 = (const float*)d_in[3];
    const float* U4 = (const float*)d_in[4];
    const float* U5 = (const float*)d_in[5];
    const int*   x  = (const int*)d_in[6];
    float* out = (float*)d_out;

    // 1024 blocks = 4 emb-chunks x 256 token-groups; 256 threads each.
    cp_embed_kernel<<<dim3(1024), dim3(256), 0, stream>>>(
        U0, U1, U2, U3, U4, U5, x, out);
}

// Round 2
// 78.051 us; speedup vs baseline: 1.0117x; 1.0117x over previous
//
#include <hip/hip_runtime.h>

// CP embedding: out[t, emb] = sum_r U0[a,r]U1[b,r]U2[c,r] * U3[d,r]U4[e,r]U5[f,r]
// where x[t] = a*1000 + b*25 + c  (a<50,b<40,c<25), emb = d*64 + e*8 + f.
// Rows with x[t]==0 (padding) are zero.
//
// Shapes: U0 (50,32) U1 (40,32) U2 (25,32) U3/U4/U5 (8,32), x (4,2048) int32,
// out (8192, 512) fp32.  Store-BW bound: 16 MB out, ~268 MFLOP fp32.
//
// R2: float4 emb-slice per thread (halves LDS broadcast reads + stores),
// phase-1 factors U3*U4 out of the U5 quad (6 loads / 4 outputs vs 12).

#define RANK 32
#define EMB 512
#define TOK_PER_BLK 32
#define EMB_CHUNK 128

__global__ __launch_bounds__(256) void cp_embed_kernel(
    const float* __restrict__ U0, const float* __restrict__ U1,
    const float* __restrict__ U2, const float* __restrict__ U3,
    const float* __restrict__ U4, const float* __restrict__ U5,
    const int*   __restrict__ x,  float* __restrict__ out)
{
    __shared__ float Wlds[RANK][EMB_CHUNK];     // [r][e_local] slice of W345^T
    __shared__ float wlds[TOK_PER_BLK][RANK];   // [t_local][r] token rank-vectors

    const int tid = threadIdx.x;
    const int c   = blockIdx.x & 3;   // emb chunk: [c*128, c*128+128)
    const int g   = blockIdx.x >> 2;  // token group: [g*32, g*32+32)

    // ---- Phase 1: build this block's 32x128 slice of W345^T in LDS ----
    // quad-aligned e shares d and e2 -> factor s = U3*U4 once per quad
    #pragma unroll
    for (int k = 0; k < 4; ++k) {
        int qd = tid + k * 256;           // quad id 0..1023
        int r  = qd >> 5;                 // rank 0..31
        int e  = (qd & 31) * 4;           // emb-local 0..124, quad-aligned
        int eg = c * EMB_CHUNK + e;       // global emb index (quad-aligned)
        int d  = eg >> 6;
        int e2 = (eg >> 3) & 7;
        int f0 = eg & 7;                  // 0 or 4
        float s = U3[d * RANK + r] * U4[e2 * RANK + r];
        float4 wv;
        wv.x = s * U5[(f0 + 0) * RANK + r];
        wv.y = s * U5[(f0 + 1) * RANK + r];
        wv.z = s * U5[(f0 + 2) * RANK + r];
        wv.w = s * U5[(f0 + 3) * RANK + r];
        *reinterpret_cast<float4*>(&Wlds[r][e]) = wv;
    }

    // ---- Phase 2: build the group's 32 token rank-vectors in LDS ----
    #pragma unroll
    for (int k = 0; k < 4; ++k) {
        int i  = tid + k * 256;           // 0..1023
        int tl = i >> 5;
        int r  = i & 31;
        int v  = x[g * TOK_PER_BLK + tl];
        float wv = 0.0f;
        if (v != 0) {                     // padding_idx = 0 -> zero row
            int a   = v / 1000;
            int rem = v - a * 1000;
            int b   = rem / 25;
            int cc  = rem - b * 25;
            wv = U0[a * RANK + r] * U1[b * RANK + r] * U2[cc * RANK + r];
        }
        wlds[tl][r] = wv;
    }

    __syncthreads();

    // ---- Phase 3: each thread owns a fixed float4 emb-slice in registers ----
    const int eq = (tid & 31) * 4;        // emb offset within chunk (0..124)
    const int ts = tid >> 5;              // token sub-slice 0..7

    float4 wt[RANK];                      // 128 VGPRs: W345^T column slice
    #pragma unroll
    for (int r = 0; r < RANK; ++r)
        wt[r] = *reinterpret_cast<const float4*>(&Wlds[r][eq]);

    #pragma unroll
    for (int k = 0; k < 4; ++k) {
        int tt = ts + k * 8;
        const float4* w4 = reinterpret_cast<const float4*>(wlds[tt]); // 2-way bcast
        float4 acc = make_float4(0.f, 0.f, 0.f, 0.f);
        #pragma unroll
        for (int rr = 0; rr < 8; ++rr) {
            float4 wv = w4[rr];
            const float4& w0 = wt[4 * rr + 0];
            const float4& w1 = wt[4 * rr + 1];
            const float4& w2 = wt[4 * rr + 2];
            const float4& w3 = wt[4 * rr + 3];
            acc.x += wv.x * w0.x; acc.y += wv.x * w0.y; acc.z += wv.x * w0.z; acc.w += wv.x * w0.w;
            acc.x += wv.y * w1.x; acc.y += wv.y * w1.y; acc.z += wv.y * w1.z; acc.w += wv.y * w1.w;
            acc.x += wv.z * w2.x; acc.y += wv.z * w2.y; acc.z += wv.z * w2.z; acc.w += wv.z * w2.w;
            acc.x += wv.w * w3.x; acc.y += wv.w * w3.y; acc.z += wv.w * w3.z; acc.w += wv.w * w3.w;
        }
        int t = g * TOK_PER_BLK + tt;
        *reinterpret_cast<float4*>(&out[t * EMB + c * EMB_CHUNK + eq]) = acc;
    }
}

extern "C" void kernel_launch(void* const* d_in, const int* in_sizes, int n_in,
                              void* d_out, int out_size, void* d_ws, size_t ws_size,
                              hipStream_t stream) {
    const float* U0 = (const float*)d_in[0];
    const float* U1 = (const float*)d_in[1];
    const float* U2 = (const float*)d_in[2];
    const float* U3 = (const float*)d_in[3];
    const float* U4 = (const float*)d_in[4];
    const float* U5 = (const float*)d_in[5];
    const int*   x  = (const int*)d_in[6];
    float* out = (float*)d_out;

    // 1024 blocks = 4 emb-chunks x 256 token-groups; 256 threads each.
    cp_embed_kernel<<<dim3(1024), dim3(256), 0, stream>>>(
        U0, U1, U2, U3, U4, U5, x, out);
}